// Round 1
// baseline (797.878 us; speedup 1.0000x reference)
//
#include <hip/hip_runtime.h>
#include <math.h>

#define V 32000
#define T 128
#define DD 64
#define NN 512

constexpr float kB     = 1.4142135623730951f;   // sqrt(2)
constexpr float kLSLO  = -2.302585092994046f;   // log(0.1)
constexpr float kLSHI  =  2.302585092994046f;   // log(10)
constexpr float kLN2   =  0.6931471805599453f;
constexpr float kDLOG2PI = 117.6241322501981f;  // 64 * log(2*pi)

__device__ __forceinline__ float clampf(float x, float lo, float hi) {
    return fminf(fmaxf(x, lo), hi);
}

// ---------------------------------------------------------------- K0: prep T-side
// stT/mucT/rcpstT stored transposed (D,T) so K1's per-d row [d][t0..t0+15] is
// contiguous -> s_load_dwordx-friendly. Also sum of clamped log_sigma_c per t.
__global__ void k_prep(const float* __restrict__ mu_c, const float* __restrict__ ls_c,
                       float* __restrict__ stT, float* __restrict__ mucT,
                       float* __restrict__ rcpstT, float* __restrict__ sumlsc) {
    int t = threadIdx.x;
    if (t >= T) return;
    float acc = 0.f;
    for (int d = 0; d < DD; ++d) {
        float lc = clampf(ls_c[t * DD + d], kLSLO, kLSHI);
        float st = __expf(lc);
        stT[d * T + t]    = st;
        rcpstT[d * T + t] = 1.0f / st;
        mucT[d * T + t]   = clampf(mu_c[t * DD + d], -kB, kB);
        acc += lc;
    }
    sumlsc[t] = acc;
}

// ---------------------------------------------------------------- K1: energy + kl
// lane = v (coalesced-ish mu/ls reads, L1-resident rows), t uniform (scalar loads).
// 16 t's per block; det_fac via product-of-16 then log2 (4 logs instead of 64).
__global__ void k_energy_kl(const float* __restrict__ mu, const float* __restrict__ ls,
                            const float* __restrict__ stT, const float* __restrict__ mucT,
                            const float* __restrict__ rcpstT, const float* __restrict__ sumlsc,
                            float* __restrict__ eT, float* __restrict__ kl_out) {
    const int t0 = blockIdx.x * 16;
    const int v  = blockIdx.y * 256 + threadIdx.x;

    float prod[16], detl[16], ae[16], atr[16], ak1[16];
    #pragma unroll
    for (int j = 0; j < 16; ++j) {
        prod[j] = 1.f; detl[j] = 0.f; ae[j] = 0.f; atr[j] = 0.f; ak1[j] = 0.f;
    }
    float slv = 0.f;

    for (int dc = 0; dc < 4; ++dc) {
        for (int dd = 0; dd < 16; ++dd) {
            const int d = dc * 16 + dd;
            float lsv = clampf(ls[(size_t)v * DD + d], kLSLO, kLSHI);
            slv += lsv;
            const float sv  = __expf(lsv);
            const float muv = clampf(mu[(size_t)v * DD + d], -kB, kB);
            #pragma unroll
            for (int j = 0; j < 16; ++j) {
                const float st = stT[d * T + t0 + j];     // uniform -> s_load
                const float mc = mucT[d * T + t0 + j];    // uniform
                const float rs = rcpstT[d * T + t0 + j];  // uniform
                const float s  = sv + st;
                prod[j] *= s;
                const float diff = muv - mc;
                const float d2   = diff * diff;
                ae[j]  = __builtin_fmaf(d2, __builtin_amdgcn_rcpf(s), ae[j]);
                atr[j] = __builtin_fmaf(sv, rs, atr[j]);
                ak1[j] = __builtin_fmaf(d2, rs, ak1[j]);
            }
        }
        #pragma unroll
        for (int j = 0; j < 16; ++j) { detl[j] += __log2f(prod[j]); prod[j] = 1.f; }
    }

    // epilogue: energy -> eT (T,V) coalesced; kl -> d_out (V,T), one 64B line/thread
    float klv[16];
    #pragma unroll
    for (int j = 0; j < 16; ++j) {
        const float energy = -0.5f * (detl[j] * kLN2 + ae[j] + kDLOG2PI);
        eT[(size_t)(t0 + j) * V + v] = energy;
        klv[j] = 0.5f * (sumlsc[t0 + j] - slv - 64.0f + atr[j] + ak1[j]);
    }
    float* kr = kl_out + (size_t)v * T + t0;
    #pragma unroll
    for (int q = 0; q < 4; ++q) {
        *reinterpret_cast<float4*>(kr + 4 * q) =
            make_float4(klv[4*q], klv[4*q+1], klv[4*q+2], klv[4*q+3]);
    }
}

// ---------------------------------------------------------------- K2a: online max/sum per column
__global__ void k_colred(const float* __restrict__ eT,
                         float* __restrict__ pmax, float* __restrict__ psum) {
    const int seg = blockIdx.x;   // 0..3, 8000 elems each
    const int t   = blockIdx.y;   // 0..127
    const float* row = eT + (size_t)t * V + seg * 8000;
    float m = -INFINITY, s = 0.f;
    for (int i = threadIdx.x; i < 8000; i += 256) {
        const float e  = row[i];
        const float nm = fmaxf(m, e);
        s = s * __expf(m - nm) + __expf(e - nm);
        m = nm;
    }
    __shared__ float sm[256], ss[256];
    sm[threadIdx.x] = m; ss[threadIdx.x] = s;
    __syncthreads();
    for (int w = 128; w > 0; w >>= 1) {
        if (threadIdx.x < w) {
            const float mA = sm[threadIdx.x], mB = sm[threadIdx.x + w];
            const float nm = fmaxf(mA, mB);
            ss[threadIdx.x] = ss[threadIdx.x] * __expf(mA - nm)
                            + ss[threadIdx.x + w] * __expf(mB - nm);
            sm[threadIdx.x] = nm;
        }
        __syncthreads();
    }
    if (threadIdx.x == 0) { pmax[t * 4 + seg] = sm[0]; psum[t * 4 + seg] = ss[0]; }
}

// ---------------------------------------------------------------- K2b: finalize per-column m, 1/den
__global__ void k_finalize(const float* __restrict__ pmax, const float* __restrict__ psum,
                           float* __restrict__ mrow, float* __restrict__ rden) {
    const int t = threadIdx.x;
    if (t >= T) return;
    float m = -INFINITY, s = 0.f;
    for (int k = 0; k < 4; ++k) {
        const float mB = pmax[t * 4 + k], sB = psum[t * 4 + k];
        const float nm = fmaxf(m, mB);
        s = s * __expf(m - nm) + sB * __expf(mB - nm);
        m = nm;
    }
    mrow[t] = m;
    rden[t] = 1.0f / s;
}

// ---------------------------------------------------------------- K2c: xs = x / den (denominator folded)
__global__ void k_scale_x(const float* __restrict__ x, const float* __restrict__ rden,
                          float* __restrict__ xs) {
    const int i = blockIdx.x * 256 + threadIdx.x;
    const int t = i >> 9;    // N = 512
    xs[i] = x[i] * rden[t];
}

// ---------------------------------------------------------------- K3: out = p @ xs  (f32 VALU GEMM)
// Block: 64 v-rows x full N. p tile in LDS (exp computed once per block);
// xs from global (16-lane broadcast, L2/L3-resident 256KB).
__global__ void __launch_bounds__(256) k_gemm(const float* __restrict__ eT,
                                              const float* __restrict__ mrow,
                                              const float* __restrict__ xs,
                                              float* __restrict__ out) {
    const int v0 = blockIdx.x * 64;
    __shared__ float pl[128][64];   // 32 KB
    for (int i = 0; i < 32; ++i) {
        const int idx = i * 256 + threadIdx.x;
        const int t = idx >> 6, vl = idx & 63;
        const float e = eT[(size_t)t * V + v0 + vl];
        pl[t][vl] = __expf(e - mrow[t]);
    }
    __syncthreads();

    const int va = (threadIdx.x & 15) * 4;  // 4 consecutive v per thread
    const int ng = threadIdx.x >> 4;        // 16 n-groups of 8
    for (int pass = 0; pass < 4; ++pass) {
        const int nb = pass * 128 + ng * 8;
        float acc[4][8];
        #pragma unroll
        for (int i = 0; i < 4; ++i)
            #pragma unroll
            for (int k = 0; k < 8; ++k) acc[i][k] = 0.f;

        #pragma unroll 2
        for (int t = 0; t < 128; ++t) {
            const float4 p4 = *reinterpret_cast<const float4*>(&pl[t][va]);
            const float4 xa = *reinterpret_cast<const float4*>(&xs[t * NN + nb]);
            const float4 xb = *reinterpret_cast<const float4*>(&xs[t * NN + nb + 4]);
            const float pv[4] = {p4.x, p4.y, p4.z, p4.w};
            const float xv[8] = {xa.x, xa.y, xa.z, xa.w, xb.x, xb.y, xb.z, xb.w};
            #pragma unroll
            for (int i = 0; i < 4; ++i)
                #pragma unroll
                for (int k = 0; k < 8; ++k)
                    acc[i][k] = __builtin_fmaf(pv[i], xv[k], acc[i][k]);
        }
        #pragma unroll
        for (int i = 0; i < 4; ++i) {
            *reinterpret_cast<float4*>(&out[(size_t)(v0 + va + i) * NN + nb]) =
                make_float4(acc[i][0], acc[i][1], acc[i][2], acc[i][3]);
            *reinterpret_cast<float4*>(&out[(size_t)(v0 + va + i) * NN + nb + 4]) =
                make_float4(acc[i][4], acc[i][5], acc[i][6], acc[i][7]);
        }
    }
}

// ---------------------------------------------------------------- launch
extern "C" void kernel_launch(void* const* d_in, const int* in_sizes, int n_in,
                              void* d_out, int out_size, void* d_ws, size_t ws_size,
                              hipStream_t stream) {
    const float* x    = (const float*)d_in[0];   // (T,N)
    const float* mu   = (const float*)d_in[1];   // (V,D)
    const float* ls   = (const float*)d_in[2];   // (V,D)
    const float* mu_c = (const float*)d_in[3];   // (T,D)
    const float* ls_c = (const float*)d_in[4];   // (T,D)
    // d_in[5] = t scalar: forward values identical for any t; ignored.

    float* out = (float*)d_out;                  // (V,N)
    float* kl  = out + (size_t)V * NN;           // (V,T)

    float* ws      = (float*)d_ws;
    float* eT      = ws;                         // T*V   (energy transposed)
    float* stT     = eT + (size_t)T * V;         // D*T
    float* mucT    = stT + DD * T;               // D*T
    float* rcpstT  = mucT + DD * T;              // D*T
    float* sumlsc  = rcpstT + DD * T;            // T
    float* pmax    = sumlsc + T;                 // T*4
    float* psum    = pmax + T * 4;               // T*4
    float* mrow    = psum + T * 4;               // T
    float* rden    = mrow + T;                   // T
    float* xs      = rden + T;                   // T*N

    k_prep<<<1, 128, 0, stream>>>(mu_c, ls_c, stT, mucT, rcpstT, sumlsc);
    k_energy_kl<<<dim3(8, 125), 256, 0, stream>>>(mu, ls, stT, mucT, rcpstT, sumlsc, eT, kl);
    k_colred<<<dim3(4, T), 256, 0, stream>>>(eT, pmax, psum);
    k_finalize<<<1, 128, 0, stream>>>(pmax, psum, mrow, rden);
    k_scale_x<<<(T * NN) / 256, 256, 0, stream>>>(x, rden, xs);
    k_gemm<<<V / 64, 256, 0, stream>>>(eT, mrow, xs, out);
}

// Round 2
// 445.275 us; speedup vs baseline: 1.7919x; 1.7919x over previous
//
#include <hip/hip_runtime.h>
#include <math.h>

#define V 32000
#define T 128
#define DD 64
#define NN 512

constexpr float kB     = 1.4142135623730951f;   // sqrt(2)
constexpr float kLSLO  = -2.302585092994046f;   // log(0.1)
constexpr float kLSHI  =  2.302585092994046f;   // log(10)
constexpr float kLN2   =  0.6931471805599453f;
constexpr float kDLOG2PI = 117.6241322501981f;  // 64 * log(2*pi)

__device__ __forceinline__ float clampf(float x, float lo, float hi) {
    return fminf(fmaxf(x, lo), hi);
}

// ---------------------------------------------------------------- K0: prep T-side
// stT/mucT/rcpstT stored transposed (D,T): K1 reads [d][t0..t0+15] rows, which
// are contiguous & wave-uniform -> scalar loads.
__global__ void k_prep(const float* __restrict__ mu_c, const float* __restrict__ ls_c,
                       float* __restrict__ stT, float* __restrict__ mucT,
                       float* __restrict__ rcpstT, float* __restrict__ sumlsc) {
    int t = threadIdx.x;
    if (t >= T) return;
    float acc = 0.f;
    for (int d = 0; d < DD; ++d) {
        float lc = clampf(ls_c[t * DD + d], kLSLO, kLSHI);
        float st = __expf(lc);
        stT[d * T + t]    = st;
        rcpstT[d * T + t] = 1.0f / st;
        mucT[d * T + t]   = clampf(mu_c[t * DD + d], -kB, kB);
        acc += lc;
    }
    sumlsc[t] = acc;
}

// ---------------------------------------------------------------- K1: energy + kl
// grid (4, V/256): 32 t's per block in two 16-wide accumulator chunks.
// Per 16-d chunk each lane loads its full 64B mu/ls line via 4 consecutive
// float4s -> full line utilization; sv/muv held in compile-time-indexed temps.
// __launch_bounds__(256,3) grants ~170 VGPRs so the 80 accumulators stay in
// registers (round-1 failure: compiler fissioned the j-loop at 48 VGPRs and
// re-read mu/ls 16x -> 2.07 GB FETCH_SIZE).
__global__ void __launch_bounds__(256, 3)
k_energy_kl(const float* __restrict__ mu, const float* __restrict__ ls,
            const float* __restrict__ stT, const float* __restrict__ mucT,
            const float* __restrict__ rcpstT, const float* __restrict__ sumlsc,
            float* __restrict__ eT, float* __restrict__ kl_out) {
    const int v = blockIdx.y * 256 + threadIdx.x;
    const float* mrow = mu + (size_t)v * DD;
    const float* lrow = ls + (size_t)v * DD;

    #pragma unroll 1
    for (int tc = 0; tc < 2; ++tc) {
        const int tt = blockIdx.x * 32 + tc * 16;
        float prod[16], detl[16], ae[16], atr[16], ak1[16];
        #pragma unroll
        for (int j = 0; j < 16; ++j) {
            prod[j] = 1.f; detl[j] = 0.f; ae[j] = 0.f; atr[j] = 0.f; ak1[j] = 0.f;
        }
        float slv = 0.f;

        #pragma unroll 1
        for (int dc = 0; dc < 4; ++dc) {
            // load one full 64B line of ls and mu (4 consecutive float4s each)
            float4 l4[4], m4[4];
            #pragma unroll
            for (int q = 0; q < 4; ++q) {
                l4[q] = *reinterpret_cast<const float4*>(lrow + dc * 16 + q * 4);
                m4[q] = *reinterpret_cast<const float4*>(mrow + dc * 16 + q * 4);
            }
            float sv[16], muv[16];
            #pragma unroll
            for (int q = 0; q < 4; ++q) {
                const float lf[4] = {l4[q].x, l4[q].y, l4[q].z, l4[q].w};
                const float mf[4] = {m4[q].x, m4[q].y, m4[q].z, m4[q].w};
                #pragma unroll
                for (int r = 0; r < 4; ++r) {
                    const float lsv = clampf(lf[r], kLSLO, kLSHI);
                    slv += lsv;
                    sv[q * 4 + r]  = __expf(lsv);
                    muv[q * 4 + r] = clampf(mf[r], -kB, kB);
                }
            }
            #pragma unroll
            for (int dd = 0; dd < 16; ++dd) {
                const int d = dc * 16 + dd;
                const float* st_r = stT    + d * T + tt;   // wave-uniform rows
                const float* mc_r = mucT   + d * T + tt;
                const float* rs_r = rcpstT + d * T + tt;
                const float svd = sv[dd], muvd = muv[dd];
                #pragma unroll
                for (int j = 0; j < 16; ++j) {
                    const float st = st_r[j];
                    const float mc = mc_r[j];
                    const float rs = rs_r[j];
                    const float s  = svd + st;
                    prod[j] *= s;
                    const float diff = muvd - mc;
                    const float d2   = diff * diff;
                    ae[j]  = __builtin_fmaf(d2, __builtin_amdgcn_rcpf(s), ae[j]);
                    atr[j] = __builtin_fmaf(svd, rs, atr[j]);
                    ak1[j] = __builtin_fmaf(d2, rs, ak1[j]);
                }
            }
            #pragma unroll
            for (int j = 0; j < 16; ++j) { detl[j] += __log2f(prod[j]); prod[j] = 1.f; }
        }

        // epilogue: energy -> eT (T,V) coalesced; kl -> d_out (V,T) one 64B line/thread
        float klv[16];
        #pragma unroll
        for (int j = 0; j < 16; ++j) {
            const float energy = -0.5f * (detl[j] * kLN2 + ae[j] + kDLOG2PI);
            eT[(size_t)(tt + j) * V + v] = energy;
            klv[j] = 0.5f * (sumlsc[tt + j] - slv - 64.0f + atr[j] + ak1[j]);
        }
        float* kr = kl_out + (size_t)v * T + tt;
        #pragma unroll
        for (int q = 0; q < 4; ++q) {
            *reinterpret_cast<float4*>(kr + 4 * q) =
                make_float4(klv[4*q], klv[4*q+1], klv[4*q+2], klv[4*q+3]);
        }
    }
}

// ---------------------------------------------------------------- K2a: online max/sum per column
__global__ void k_colred(const float* __restrict__ eT,
                         float* __restrict__ pmax, float* __restrict__ psum) {
    const int seg = blockIdx.x;   // 0..3, 8000 elems each
    const int t   = blockIdx.y;   // 0..127
    const float* row = eT + (size_t)t * V + seg * 8000;
    float m = -INFINITY, s = 0.f;
    for (int i = threadIdx.x; i < 8000; i += 256) {
        const float e  = row[i];
        const float nm = fmaxf(m, e);
        s = s * __expf(m - nm) + __expf(e - nm);
        m = nm;
    }
    __shared__ float sm[256], ss[256];
    sm[threadIdx.x] = m; ss[threadIdx.x] = s;
    __syncthreads();
    for (int w = 128; w > 0; w >>= 1) {
        if (threadIdx.x < w) {
            const float mA = sm[threadIdx.x], mB = sm[threadIdx.x + w];
            const float nm = fmaxf(mA, mB);
            ss[threadIdx.x] = ss[threadIdx.x] * __expf(mA - nm)
                            + ss[threadIdx.x + w] * __expf(mB - nm);
            sm[threadIdx.x] = nm;
        }
        __syncthreads();
    }
    if (threadIdx.x == 0) { pmax[t * 4 + seg] = sm[0]; psum[t * 4 + seg] = ss[0]; }
}

// ---------------------------------------------------------------- K2b: finalize per-column m, 1/den
__global__ void k_finalize(const float* __restrict__ pmax, const float* __restrict__ psum,
                           float* __restrict__ mrow, float* __restrict__ rden) {
    const int t = threadIdx.x;
    if (t >= T) return;
    float m = -INFINITY, s = 0.f;
    for (int k = 0; k < 4; ++k) {
        const float mB = pmax[t * 4 + k], sB = psum[t * 4 + k];
        const float nm = fmaxf(m, mB);
        s = s * __expf(m - nm) + sB * __expf(mB - nm);
        m = nm;
    }
    mrow[t] = m;
    rden[t] = 1.0f / s;
}

// ---------------------------------------------------------------- K2c: xs = x / den
__global__ void k_scale_x(const float* __restrict__ x, const float* __restrict__ rden,
                          float* __restrict__ xs) {
    const int i = blockIdx.x * 256 + threadIdx.x;
    const int t = i >> 9;    // N = 512
    xs[i] = x[i] * rden[t];
}

// ---------------------------------------------------------------- K3: out = p @ xs  (f32 VALU GEMM)
__global__ void __launch_bounds__(256) k_gemm(const float* __restrict__ eT,
                                              const float* __restrict__ mrow,
                                              const float* __restrict__ xs,
                                              float* __restrict__ out) {
    const int v0 = blockIdx.x * 64;
    __shared__ float pl[128][64];   // 32 KB
    for (int i = 0; i < 32; ++i) {
        const int idx = i * 256 + threadIdx.x;
        const int t = idx >> 6, vl = idx & 63;
        const float e = eT[(size_t)t * V + v0 + vl];
        pl[t][vl] = __expf(e - mrow[t]);
    }
    __syncthreads();

    const int va = (threadIdx.x & 15) * 4;  // 4 consecutive v per thread
    const int ng = threadIdx.x >> 4;        // 16 n-groups of 8
    for (int pass = 0; pass < 4; ++pass) {
        const int nb = pass * 128 + ng * 8;
        float acc[4][8];
        #pragma unroll
        for (int i = 0; i < 4; ++i)
            #pragma unroll
            for (int k = 0; k < 8; ++k) acc[i][k] = 0.f;

        #pragma unroll 2
        for (int t = 0; t < 128; ++t) {
            const float4 p4 = *reinterpret_cast<const float4*>(&pl[t][va]);
            const float4 xa = *reinterpret_cast<const float4*>(&xs[t * NN + nb]);
            const float4 xb = *reinterpret_cast<const float4*>(&xs[t * NN + nb + 4]);
            const float pv[4] = {p4.x, p4.y, p4.z, p4.w};
            const float xv[8] = {xa.x, xa.y, xa.z, xa.w, xb.x, xb.y, xb.z, xb.w};
            #pragma unroll
            for (int i = 0; i < 4; ++i)
                #pragma unroll
                for (int k = 0; k < 8; ++k)
                    acc[i][k] = __builtin_fmaf(pv[i], xv[k], acc[i][k]);
        }
        #pragma unroll
        for (int i = 0; i < 4; ++i) {
            *reinterpret_cast<float4*>(&out[(size_t)(v0 + va + i) * NN + nb]) =
                make_float4(acc[i][0], acc[i][1], acc[i][2], acc[i][3]);
            *reinterpret_cast<float4*>(&out[(size_t)(v0 + va + i) * NN + nb + 4]) =
                make_float4(acc[i][4], acc[i][5], acc[i][6], acc[i][7]);
        }
    }
}

// ---------------------------------------------------------------- launch
extern "C" void kernel_launch(void* const* d_in, const int* in_sizes, int n_in,
                              void* d_out, int out_size, void* d_ws, size_t ws_size,
                              hipStream_t stream) {
    const float* x    = (const float*)d_in[0];   // (T,N)
    const float* mu   = (const float*)d_in[1];   // (V,D)
    const float* ls   = (const float*)d_in[2];   // (V,D)
    const float* mu_c = (const float*)d_in[3];   // (T,D)
    const float* ls_c = (const float*)d_in[4];   // (T,D)
    // d_in[5] = t scalar: forward values identical for any t; ignored.

    float* out = (float*)d_out;                  // (V,N)
    float* kl  = out + (size_t)V * NN;           // (V,T)

    float* ws      = (float*)d_ws;
    float* eT      = ws;                         // T*V   (energy transposed)
    float* stT     = eT + (size_t)T * V;         // D*T
    float* mucT    = stT + DD * T;               // D*T
    float* rcpstT  = mucT + DD * T;              // D*T
    float* sumlsc  = rcpstT + DD * T;            // T
    float* pmax    = sumlsc + T;                 // T*4
    float* psum    = pmax + T * 4;               // T*4
    float* mrow    = psum + T * 4;               // T
    float* rden    = mrow + T;                   // T
    float* xs      = rden + T;                   // T*N

    k_prep<<<1, 128, 0, stream>>>(mu_c, ls_c, stT, mucT, rcpstT, sumlsc);
    k_energy_kl<<<dim3(4, V / 256), 256, 0, stream>>>(mu, ls, stT, mucT, rcpstT, sumlsc, eT, kl);
    k_colred<<<dim3(4, T), 256, 0, stream>>>(eT, pmax, psum);
    k_finalize<<<1, 128, 0, stream>>>(pmax, psum, mrow, rden);
    k_scale_x<<<(T * NN) / 256, 256, 0, stream>>>(x, rden, xs);
    k_gemm<<<V / 64, 256, 0, stream>>>(eT, mrow, xs, out);
}

// Round 4
// 291.037 us; speedup vs baseline: 2.7415x; 1.5300x over previous
//
#include <hip/hip_runtime.h>
#include <math.h>

#define V 32000
#define T 128
#define DD 64
#define NN 512

constexpr float kB     = 1.4142135623730951f;   // sqrt(2)
constexpr float kLSLO  = -2.302585092994046f;   // log(0.1)
constexpr float kLSHI  =  2.302585092994046f;   // log(10)
constexpr float kLN2   =  0.6931471805599453f;
constexpr float kDLOG2PI = 117.6241322501981f;  // 64 * log(2*pi)

__device__ __forceinline__ float clampf(float x, float lo, float hi) {
    return fminf(fmaxf(x, lo), hi);
}

// ---------------------------------------------------------------- K0: prep T-side
// (T,D) layout: K1's per-t rows are contiguous + wave-uniform -> s_load chunks.
__global__ void k_prep(const float* __restrict__ mu_c, const float* __restrict__ ls_c,
                       float* __restrict__ st_td, float* __restrict__ mc_td,
                       float* __restrict__ rs_td, float* __restrict__ sumlsc) {
    int t = threadIdx.x;
    if (t >= T) return;
    float acc = 0.f;
    for (int d = 0; d < DD; ++d) {
        float lc = clampf(ls_c[t * DD + d], kLSLO, kLSHI);
        float st = __expf(lc);
        st_td[t * DD + d] = st;
        rs_td[t * DD + d] = 1.0f / st;
        mc_td[t * DD + d] = clampf(mu_c[t * DD + d], -kB, kB);
        acc += lc;
    }
    sumlsc[t] = acc;
}

// ---------------------------------------------------------------- K1: energy + kl
// t-inner structure: each thread holds its mu/ls row as sv[64]/muv[64]
// (long-lived read-only regs) and walks 32 t's with SCALAR accumulators.
// Round-2 failure: 80-wide accumulator tile + unrolled 16x16 body spilled
// (WRITE_SIZE 414MB vs 33MB ideal at VGPR=84). This shape needs ~145 live regs,
// all statically indexed. kl goes through an LDS transpose tile so the (V,T)
// store is line-coalesced.
__global__ void __launch_bounds__(256, 2)
k_energy_kl(const float* __restrict__ mu, const float* __restrict__ ls,
            const float* __restrict__ st_td, const float* __restrict__ mc_td,
            const float* __restrict__ rs_td, const float* __restrict__ sumlsc,
            float* __restrict__ eT, float* __restrict__ kl_out) {
    const int v  = blockIdx.y * 256 + threadIdx.x;
    const int t0 = blockIdx.x * 32;

    __shared__ float klt[32][257];   // [t_local][v_local], pad -> conflict-free both phases

    // Phase A: load own row, precompute sv / muv / slv
    float sv[DD], muv[DD];
    float slv = 0.f;
    const float* lrow = ls + (size_t)v * DD;
    const float* mrow = mu + (size_t)v * DD;
    #pragma unroll
    for (int q = 0; q < DD / 4; ++q) {
        const float4 l4 = *reinterpret_cast<const float4*>(lrow + q * 4);
        const float4 m4 = *reinterpret_cast<const float4*>(mrow + q * 4);
        const float lf[4] = {l4.x, l4.y, l4.z, l4.w};
        const float mf[4] = {m4.x, m4.y, m4.z, m4.w};
        #pragma unroll
        for (int r = 0; r < 4; ++r) {
            const float lsv = clampf(lf[r], kLSLO, kLSHI);
            slv += lsv;
            sv[q * 4 + r]  = __expf(lsv);
            muv[q * 4 + r] = clampf(mf[r], -kB, kB);
        }
    }

    // Phase B: walk 32 t's, scalar accumulators only
    #pragma unroll 1
    for (int tl = 0; tl < 32; ++tl) {
        const int t = t0 + tl;
        const float* st_r = st_td + t * DD;   // wave-uniform rows
        const float* mc_r = mc_td + t * DD;
        const float* rs_r = rs_td + t * DD;
        float det = 0.f, ae = 0.f, akl = 0.f;
        #pragma unroll
        for (int dc = 0; dc < 4; ++dc) {
            float prod = 1.f;
            #pragma unroll
            for (int dd = 0; dd < 16; ++dd) {
                const int d = dc * 16 + dd;
                const float st = st_r[d];
                const float mc = mc_r[d];
                const float rs = rs_r[d];
                const float s  = sv[d] + st;
                prod *= s;
                const float diff = muv[d] - mc;
                const float d2   = diff * diff;
                ae  = __builtin_fmaf(d2, __builtin_amdgcn_rcpf(s), ae);
                akl = __builtin_fmaf(sv[d] + d2, rs, akl);
            }
            det += __log2f(prod);
        }
        eT[(size_t)t * V + v] = -0.5f * (det * kLN2 + ae + kDLOG2PI);
        klt[tl][threadIdx.x] = 0.5f * (sumlsc[t] - slv - 64.0f + akl);
    }

    // Phase C: LDS-transposed kl store, line-coalesced.
    // pass p: half-wave (32 lanes) covers one v-row's 32 t's (128B contiguous).
    __syncthreads();
    const int tc = threadIdx.x & 31;
    const int vb = threadIdx.x >> 5;    // 0..7
    #pragma unroll 1
    for (int p = 0; p < 32; ++p) {
        const int vl = p * 8 + vb;
        kl_out[(size_t)(blockIdx.y * 256 + vl) * T + t0 + tc] = klt[tc][vl];
    }
}

// ---------------------------------------------------------------- K2a: online max/sum per column
__global__ void k_colred(const float* __restrict__ eT,
                         float* __restrict__ pmax, float* __restrict__ psum) {
    const int seg = blockIdx.x;   // 0..3, 8000 elems each
    const int t   = blockIdx.y;   // 0..127
    const float* row = eT + (size_t)t * V + seg * 8000;
    float m = -INFINITY, s = 0.f;
    for (int i = threadIdx.x; i < 8000; i += 256) {
        const float e  = row[i];
        const float nm = fmaxf(m, e);
        s = s * __expf(m - nm) + __expf(e - nm);
        m = nm;
    }
    __shared__ float sm[256], ss[256];
    sm[threadIdx.x] = m; ss[threadIdx.x] = s;
    __syncthreads();
    for (int w = 128; w > 0; w >>= 1) {
        if (threadIdx.x < w) {
            const float mA = sm[threadIdx.x], mB = sm[threadIdx.x + w];
            const float nm = fmaxf(mA, mB);
            ss[threadIdx.x] = ss[threadIdx.x] * __expf(mA - nm)
                            + ss[threadIdx.x + w] * __expf(mB - nm);
            sm[threadIdx.x] = nm;
        }
        __syncthreads();
    }
    if (threadIdx.x == 0) { pmax[t * 4 + seg] = sm[0]; psum[t * 4 + seg] = ss[0]; }
}

// ---------------------------------------------------------------- K2b: finalize per-column m, 1/den
__global__ void k_finalize(const float* __restrict__ pmax, const float* __restrict__ psum,
                           float* __restrict__ mrow, float* __restrict__ rden) {
    const int t = threadIdx.x;
    if (t >= T) return;
    float m = -INFINITY, s = 0.f;
    for (int k = 0; k < 4; ++k) {
        const float mB = pmax[t * 4 + k], sB = psum[t * 4 + k];
        const float nm = fmaxf(m, mB);
        s = s * __expf(m - nm) + sB * __expf(mB - nm);
        m = nm;
    }
    mrow[t] = m;
    rden[t] = 1.0f / s;
}

// ---------------------------------------------------------------- K2c: xs = x / den
__global__ void k_scale_x(const float* __restrict__ x, const float* __restrict__ rden,
                          float* __restrict__ xs) {
    const int i = blockIdx.x * 256 + threadIdx.x;
    const int t = i >> 9;    // N = 512
    xs[i] = x[i] * rden[t];
}

// ---------------------------------------------------------------- K3: out = p @ xs  (f32 VALU GEMM)
__global__ void __launch_bounds__(256) k_gemm(const float* __restrict__ eT,
                                              const float* __restrict__ mrow,
                                              const float* __restrict__ xs,
                                              float* __restrict__ out) {
    const int v0 = blockIdx.x * 64;
    __shared__ float pl[128][64];   // 32 KB
    for (int i = 0; i < 32; ++i) {
        const int idx = i * 256 + threadIdx.x;
        const int t = idx >> 6, vl = idx & 63;
        const float e = eT[(size_t)t * V + v0 + vl];
        pl[t][vl] = __expf(e - mrow[t]);
    }
    __syncthreads();

    const int va = (threadIdx.x & 15) * 4;  // 4 consecutive v per thread
    const int ng = threadIdx.x >> 4;        // 16 n-groups of 8
    for (int pass = 0; pass < 4; ++pass) {
        const int nb = pass * 128 + ng * 8;
        float acc[4][8];
        #pragma unroll
        for (int i = 0; i < 4; ++i)
            #pragma unroll
            for (int k = 0; k < 8; ++k) acc[i][k] = 0.f;

        #pragma unroll 2
        for (int t = 0; t < 128; ++t) {
            const float4 p4 = *reinterpret_cast<const float4*>(&pl[t][va]);
            const float4 xa = *reinterpret_cast<const float4*>(&xs[t * NN + nb]);
            const float4 xb = *reinterpret_cast<const float4*>(&xs[t * NN + nb + 4]);
            const float pv[4] = {p4.x, p4.y, p4.z, p4.w};
            const float xv[8] = {xa.x, xa.y, xa.z, xa.w, xb.x, xb.y, xb.z, xb.w};
            #pragma unroll
            for (int i = 0; i < 4; ++i)
                #pragma unroll
                for (int k = 0; k < 8; ++k)
                    acc[i][k] = __builtin_fmaf(pv[i], xv[k], acc[i][k]);
        }
        #pragma unroll
        for (int i = 0; i < 4; ++i) {
            *reinterpret_cast<float4*>(&out[(size_t)(v0 + va + i) * NN + nb]) =
                make_float4(acc[i][0], acc[i][1], acc[i][2], acc[i][3]);
            *reinterpret_cast<float4*>(&out[(size_t)(v0 + va + i) * NN + nb + 4]) =
                make_float4(acc[i][4], acc[i][5], acc[i][6], acc[i][7]);
        }
    }
}

// ---------------------------------------------------------------- launch
extern "C" void kernel_launch(void* const* d_in, const int* in_sizes, int n_in,
                              void* d_out, int out_size, void* d_ws, size_t ws_size,
                              hipStream_t stream) {
    const float* x    = (const float*)d_in[0];   // (T,N)
    const float* mu   = (const float*)d_in[1];   // (V,D)
    const float* ls   = (const float*)d_in[2];   // (V,D)
    const float* mu_c = (const float*)d_in[3];   // (T,D)
    const float* ls_c = (const float*)d_in[4];   // (T,D)
    // d_in[5] = t scalar: forward values identical for any t; ignored.

    float* out = (float*)d_out;                  // (V,N)
    float* kl  = out + (size_t)V * NN;           // (V,T)

    float* ws      = (float*)d_ws;
    float* eT      = ws;                         // T*V   (energy transposed)
    float* st_td   = eT + (size_t)T * V;         // T*D
    float* mc_td   = st_td + T * DD;             // T*D
    float* rs_td   = mc_td + T * DD;             // T*D
    float* sumlsc  = rs_td + T * DD;             // T
    float* pmax    = sumlsc + T;                 // T*4
    float* psum    = pmax + T * 4;               // T*4
    float* mrow    = psum + T * 4;               // T
    float* rden    = mrow + T;                   // T
    float* xs      = rden + T;                   // T*N

    k_prep<<<1, 128, 0, stream>>>(mu_c, ls_c, st_td, mc_td, rs_td, sumlsc);
    k_energy_kl<<<dim3(4, V / 256), 256, 0, stream>>>(mu, ls, st_td, mc_td, rs_td, sumlsc, eT, kl);
    k_colred<<<dim3(4, T), 256, 0, stream>>>(eT, pmax, psum);
    k_finalize<<<1, 128, 0, stream>>>(pmax, psum, mrow, rden);
    k_scale_x<<<(T * NN) / 256, 256, 0, stream>>>(x, rden, xs);
    k_gemm<<<V / 64, 256, 0, stream>>>(eT, mrow, xs, out);
}

// Round 9
// 283.054 us; speedup vs baseline: 2.8188x; 1.0282x over previous
//
#include <hip/hip_runtime.h>
#include <math.h>

#define V 32000
#define T 128
#define DD 64
#define NN 512

typedef float f32x4 __attribute__((ext_vector_type(4)));  // native vec for nontemporal builtin

constexpr float kB     = 1.4142135623730951f;   // sqrt(2)
constexpr float kLSLO  = -2.302585092994046f;   // log(0.1)
constexpr float kLSHI  =  2.302585092994046f;   // log(10)
constexpr float kLN2   =  0.6931471805599453f;
constexpr float kDLOG2PI = 117.6241322501981f;  // 64 * log(2*pi)

__device__ __forceinline__ float clampf(float x, float lo, float hi) {
    return fminf(fmaxf(x, lo), hi);
}

// ---------------------------------------------------------------- K0: prep T-side
// (T,D) layout: K1's per-t rows are contiguous + wave-uniform -> s_load chunks.
__global__ void k_prep(const float* __restrict__ mu_c, const float* __restrict__ ls_c,
                       float* __restrict__ st_td, float* __restrict__ mc_td,
                       float* __restrict__ rs_td, float* __restrict__ sumlsc) {
    int t = threadIdx.x;
    if (t >= T) return;
    float acc = 0.f;
    for (int d = 0; d < DD; ++d) {
        float lc = clampf(ls_c[t * DD + d], kLSLO, kLSHI);
        float st = __expf(lc);
        st_td[t * DD + d] = st;
        rs_td[t * DD + d] = 1.0f / st;
        mc_td[t * DD + d] = clampf(mu_c[t * DD + d], -kB, kB);
        acc += lc;
    }
    sumlsc[t] = acc;
}

// ---------------------------------------------------------------- K1: energy + kl
// t-inner structure: each thread holds its mu/ls row as sv[64]/muv[64]
// (long-lived read-only regs) and walks 32 t's with SCALAR accumulators.
// (Round-2 failure was an 80-wide accumulator tile -> spills at VGPR=84.)
__global__ void __launch_bounds__(256, 2)
k_energy_kl(const float* __restrict__ mu, const float* __restrict__ ls,
            const float* __restrict__ st_td, const float* __restrict__ mc_td,
            const float* __restrict__ rs_td, const float* __restrict__ sumlsc,
            float* __restrict__ eT, float* __restrict__ kl_out) {
    const int v  = blockIdx.y * 256 + threadIdx.x;
    const int t0 = blockIdx.x * 32;

    __shared__ float klt[32][257];   // [t_local][v_local], pad -> conflict-free both phases

    // Phase A: load own row, precompute sv / muv / slv
    float sv[DD], muv[DD];
    float slv = 0.f;
    const float* lrow = ls + (size_t)v * DD;
    const float* mrow = mu + (size_t)v * DD;
    #pragma unroll
    for (int q = 0; q < DD / 4; ++q) {
        const float4 l4 = *reinterpret_cast<const float4*>(lrow + q * 4);
        const float4 m4 = *reinterpret_cast<const float4*>(mrow + q * 4);
        const float lf[4] = {l4.x, l4.y, l4.z, l4.w};
        const float mf[4] = {m4.x, m4.y, m4.z, m4.w};
        #pragma unroll
        for (int r = 0; r < 4; ++r) {
            const float lsv = clampf(lf[r], kLSLO, kLSHI);
            slv += lsv;
            sv[q * 4 + r]  = __expf(lsv);
            muv[q * 4 + r] = clampf(mf[r], -kB, kB);
        }
    }

    // Phase B: walk 32 t's, scalar accumulators only
    #pragma unroll 1
    for (int tl = 0; tl < 32; ++tl) {
        const int t = t0 + tl;
        const float* st_r = st_td + t * DD;   // wave-uniform rows
        const float* mc_r = mc_td + t * DD;
        const float* rs_r = rs_td + t * DD;
        float det = 0.f, ae = 0.f, akl = 0.f;
        #pragma unroll
        for (int dc = 0; dc < 4; ++dc) {
            float prod = 1.f;
            #pragma unroll
            for (int dd = 0; dd < 16; ++dd) {
                const int d = dc * 16 + dd;
                const float st = st_r[d];
                const float mc = mc_r[d];
                const float rs = rs_r[d];
                const float s  = sv[d] + st;
                prod *= s;
                const float diff = muv[d] - mc;
                const float d2   = diff * diff;
                ae  = __builtin_fmaf(d2, __builtin_amdgcn_rcpf(s), ae);
                akl = __builtin_fmaf(sv[d] + d2, rs, akl);
            }
            det += __log2f(prod);
        }
        eT[(size_t)t * V + v] = -0.5f * (det * kLN2 + ae + kDLOG2PI);
        klt[tl][threadIdx.x] = 0.5f * (sumlsc[t] - slv - 64.0f + akl);
    }

    // Phase C: LDS-transposed kl store, line-coalesced.
    __syncthreads();
    const int tc = threadIdx.x & 31;
    const int vb = threadIdx.x >> 5;    // 0..7
    #pragma unroll 1
    for (int p = 0; p < 32; ++p) {
        const int vl = p * 8 + vb;
        kl_out[(size_t)(blockIdx.y * 256 + vl) * T + t0 + tc] = klt[tc][vl];
    }
}

// ---------------------------------------------------------------- K2a: online max/sum per column
__global__ void k_colred(const float* __restrict__ eT,
                         float* __restrict__ pmax, float* __restrict__ psum) {
    const int seg = blockIdx.x;   // 0..3, 8000 elems each
    const int t   = blockIdx.y;   // 0..127
    const float* row = eT + (size_t)t * V + seg * 8000;
    float m = -INFINITY, s = 0.f;
    for (int i = threadIdx.x; i < 8000; i += 256) {
        const float e  = row[i];
        const float nm = fmaxf(m, e);
        s = s * __expf(m - nm) + __expf(e - nm);
        m = nm;
    }
    __shared__ float sm[256], ss[256];
    sm[threadIdx.x] = m; ss[threadIdx.x] = s;
    __syncthreads();
    for (int w = 128; w > 0; w >>= 1) {
        if (threadIdx.x < w) {
            const float mA = sm[threadIdx.x], mB = sm[threadIdx.x + w];
            const float nm = fmaxf(mA, mB);
            ss[threadIdx.x] = ss[threadIdx.x] * __expf(mA - nm)
                            + ss[threadIdx.x + w] * __expf(mB - nm);
            sm[threadIdx.x] = nm;
        }
        __syncthreads();
    }
    if (threadIdx.x == 0) { pmax[t * 4 + seg] = sm[0]; psum[t * 4 + seg] = ss[0]; }
}

// ---------------------------------------------------------------- K2b: finalize per-column m, 1/den
__global__ void k_finalize(const float* __restrict__ pmax, const float* __restrict__ psum,
                           float* __restrict__ mrow, float* __restrict__ rden) {
    const int t = threadIdx.x;
    if (t >= T) return;
    float m = -INFINITY, s = 0.f;
    for (int k = 0; k < 4; ++k) {
        const float mB = pmax[t * 4 + k], sB = psum[t * 4 + k];
        const float nm = fmaxf(m, mB);
        s = s * __expf(m - nm) + sB * __expf(mB - nm);
        m = nm;
    }
    mrow[t] = m;
    rden[t] = 1.0f / s;
}

// ---------------------------------------------------------------- K2c: xs = x / den
__global__ void k_scale_x(const float* __restrict__ x, const float* __restrict__ rden,
                          float* __restrict__ xs) {
    const int i = blockIdx.x * 256 + threadIdx.x;
    const int t = i >> 9;    // N = 512
    xs[i] = x[i] * rden[t];
}

// ---------------------------------------------------------------- K3: out = p @ xs  (f32 VALU GEMM)
// Round-4: 500 blocks = 1.95/CU = 20% occupancy -> latency-bound (VALUBusy 32%).
// Split N across blockIdx.y (4 x 128 cols): 2000 blocks, LDS caps 5 blocks/CU
// = 62% occupancy. Extra cost: p-tile staged 4x (eT re-reads are L3-resident).
__global__ void __launch_bounds__(256) k_gemm(const float* __restrict__ eT,
                                              const float* __restrict__ mrow,
                                              const float* __restrict__ xs,
                                              float* __restrict__ out) {
    const int v0   = blockIdx.x * 64;
    const int pass = blockIdx.y;
    __shared__ float pl[128][64];   // 32 KB
    for (int i = 0; i < 32; ++i) {
        const int idx = i * 256 + threadIdx.x;
        const int t = idx >> 6, vl = idx & 63;
        const float e = eT[(size_t)t * V + v0 + vl];
        pl[t][vl] = __expf(e - mrow[t]);
    }
    __syncthreads();

    const int va = (threadIdx.x & 15) * 4;  // 4 consecutive v per thread
    const int ng = threadIdx.x >> 4;        // 16 n-groups of 8
    const int nb = pass * 128 + ng * 8;

    float acc[4][8];
    #pragma unroll
    for (int i = 0; i < 4; ++i)
        #pragma unroll
        for (int k = 0; k < 8; ++k) acc[i][k] = 0.f;

    #pragma unroll 2
    for (int t = 0; t < 128; ++t) {
        const float4 p4 = *reinterpret_cast<const float4*>(&pl[t][va]);
        const float4 xa = *reinterpret_cast<const float4*>(&xs[t * NN + nb]);
        const float4 xb = *reinterpret_cast<const float4*>(&xs[t * NN + nb + 4]);
        const float pv[4] = {p4.x, p4.y, p4.z, p4.w};
        const float xv[8] = {xa.x, xa.y, xa.z, xa.w, xb.x, xb.y, xb.z, xb.w};
        #pragma unroll
        for (int i = 0; i < 4; ++i)
            #pragma unroll
            for (int k = 0; k < 8; ++k)
                acc[i][k] = __builtin_fmaf(pv[i], xv[k], acc[i][k]);
    }
    #pragma unroll
    for (int i = 0; i < 4; ++i) {
        f32x4 lo = {acc[i][0], acc[i][1], acc[i][2], acc[i][3]};
        f32x4 hi = {acc[i][4], acc[i][5], acc[i][6], acc[i][7]};
        __builtin_nontemporal_store(lo,
            reinterpret_cast<f32x4*>(&out[(size_t)(v0 + va + i) * NN + nb]));
        __builtin_nontemporal_store(hi,
            reinterpret_cast<f32x4*>(&out[(size_t)(v0 + va + i) * NN + nb + 4]));
    }
}

// ---------------------------------------------------------------- launch
extern "C" void kernel_launch(void* const* d_in, const int* in_sizes, int n_in,
                              void* d_out, int out_size, void* d_ws, size_t ws_size,
                              hipStream_t stream) {
    const float* x    = (const float*)d_in[0];   // (T,N)
    const float* mu   = (const float*)d_in[1];   // (V,D)
    const float* ls   = (const float*)d_in[2];   // (V,D)
    const float* mu_c = (const float*)d_in[3];   // (T,D)
    const float* ls_c = (const float*)d_in[4];   // (T,D)
    // d_in[5] = t scalar: forward values identical for any t; ignored.

    float* out = (float*)d_out;                  // (V,N)
    float* kl  = out + (size_t)V * NN;           // (V,T)

    float* ws      = (float*)d_ws;
    float* eT      = ws;                         // T*V   (energy transposed)
    float* st_td   = eT + (size_t)T * V;         // T*D
    float* mc_td   = st_td + T * DD;             // T*D
    float* rs_td   = mc_td + T * DD;             // T*D
    float* sumlsc  = rs_td + T * DD;             // T
    float* pmax    = sumlsc + T;                 // T*4
    float* psum    = pmax + T * 4;               // T*4
    float* mrow    = psum + T * 4;               // T
    float* rden    = mrow + T;                   // T
    float* xs      = rden + T;                   // T*N

    k_prep<<<1, 128, 0, stream>>>(mu_c, ls_c, st_td, mc_td, rs_td, sumlsc);
    k_energy_kl<<<dim3(4, V / 256), 256, 0, stream>>>(mu, ls, st_td, mc_td, rs_td, sumlsc, eT, kl);
    k_colred<<<dim3(4, T), 256, 0, stream>>>(eT, pmax, psum);
    k_finalize<<<1, 128, 0, stream>>>(pmax, psum, mrow, rden);
    k_scale_x<<<(T * NN) / 256, 256, 0, stream>>>(x, rden, xs);
    k_gemm<<<dim3(V / 64, 4), 256, 0, stream>>>(eT, mrow, xs, out);
}